// Round 3
// baseline (39.450 us; speedup 1.0000x reference)
//
#include <hip/hip_runtime.h>
#include <math.h>

// QuantumGenerator: 4-qubit, 2-layer StronglyEntanglingLayers circuit + Linear(4,4).
// out_j(x) = sum_{p in {I,Z,Y}^4} D_j[p] * prod_w f_{p_w}(x_w),  f = (1, cos, -sin).
// qg_precompute builds the 81x4 coefficient table D (bias folded into all-I term),
// parallelized across the block (shfl-distributed 16x16 unitary build).
// qg_main: E=2 elements/thread, named float2 scalars, D staged in LDS (uniform
// ds_read_b128 broadcast -- no reliance on global-load scalarization).

__global__ __launch_bounds__(256) void qg_precompute(
    const float* __restrict__ qw,   // [2][4][3] (phi, theta, omega)
    const float* __restrict__ Wm,   // [4][4]
    const float* __restrict__ bv,   // [4]
    float* __restrict__ Dcoef)      // [81][4]
{
  __shared__ float  gm[24][8];      // per-gate 2x2 complex matrix
  __shared__ float2 Ul[16][16];     // U[k][col]
  __shared__ float  wj[4][16];
  __shared__ float2 A[4][16][16];
  const int tid = threadIdx.x;

  // ---- gate matrices, 24 threads in parallel ----
  if (tid < 24) {
    const float phi = qw[tid*3 + 0];
    const float th  = qw[tid*3 + 1];
    const float om  = qw[tid*3 + 2];
    float st, ct, sa, ca, sd, cd;
    __sincosf(0.5f*th,       &st, &ct);
    __sincosf(0.5f*(phi+om), &sa, &ca);
    __sincosf(0.5f*(phi-om), &sd, &cd);
    gm[tid][0] =  ca*ct; gm[tid][1] = -sa*ct;   // m00
    gm[tid][2] = -cd*st; gm[tid][3] = -sd*st;   // m01
    gm[tid][4] =  cd*st; gm[tid][5] = -sd*st;   // m10
    gm[tid][6] =  ca*ct; gm[tid][7] =  sa*ct;   // m11
  }
  // ---- wj[j][k] = sum_i W[j,i]*(1-2*bit_i(k)), 64 threads (wave 3) ----
  if (tid >= 192) {
    const int j = (tid - 192) >> 4, k = tid & 15;
    float s = 0.f;
    #pragma unroll
    for (int i = 0; i < 4; ++i)
      s += Wm[j*4 + i] * (((k >> (3 - i)) & 1) ? -1.f : 1.f);
    wj[j][k] = s;
  }
  __syncthreads();

  // ---- U build: one matrix element per thread, shfl butterflies ----
  {
    const int col = tid >> 4, row = tid & 15;
    float vr = (row == col) ? 1.f : 0.f, vi = 0.f;
    #pragma unroll
    for (int l = 0; l < 2; ++l) {
      #pragma unroll
      for (int w = 0; w < 4; ++w) {
        const int g = l*4 + w;
        const float m00r = gm[g][0], m00i = gm[g][1];
        const float m01r = gm[g][2], m01i = gm[g][3];
        const float m10r = gm[g][4], m10i = gm[g][5];
        const float m11r = gm[g][6], m11i = gm[g][7];
        const int mask = 8 >> w;
        const float pr = __shfl_xor(vr, mask);
        const float pi = __shfl_xor(vi, mask);
        float nr, ni;
        if (!(row & mask)) {   // this thread holds v0; partner holds v1
          nr = m00r*vr - m00i*vi + m01r*pr - m01i*pi;
          ni = m00r*vi + m00i*vr + m01r*pi + m01i*pr;
        } else {               // this thread holds v1; partner holds v0
          nr = m10r*pr - m10i*pi + m11r*vr - m11i*vi;
          ni = m10r*pi + m10i*pr + m11r*vi + m11i*vr;
        }
        vr = nr; vi = ni;
      }
      const int r = l + 1;     // StronglyEntanglingLayers ranges for 2 layers
      #pragma unroll
      for (int w = 0; w < 4; ++w) {
        const int t  = (w + r) & 3;
        const int cm = 8 >> w, tm = 8 >> t;
        const float pr = __shfl_xor(vr, tm);
        const float pi = __shfl_xor(vi, tm);
        if (row & cm) { vr = pr; vi = pi; }  // swap target bit where control=1
      }
    }
    Ul[row][col] = make_float2(vr, vi);
  }
  __syncthreads();

  // ---- A[j][s][t] = sum_k conj(U[k][s]) wj[j][k] U[k][t] ----
  {
    const int s = tid >> 4, t = tid & 15;
    float ar[4] = {0,0,0,0}, ai[4] = {0,0,0,0};
    #pragma unroll
    for (int k = 0; k < 16; ++k) {
      const float2 us = Ul[k][s], ut = Ul[k][t];
      const float pr = us.x*ut.x + us.y*ut.y;
      const float pi = us.x*ut.y - us.y*ut.x;
      #pragma unroll
      for (int j = 0; j < 4; ++j) { ar[j] += wj[j][k]*pr; ai[j] += wj[j][k]*pi; }
    }
    #pragma unroll
    for (int j = 0; j < 4; ++j) A[j][s][t] = make_float2(ar[j], ai[j]);
  }
  __syncthreads();

  // ---- D_j[p] = (1/16) Tr(A_j sigma_p), sigma in {I,Z,Y}^4 ----
  for (int item = tid; item < 324; item += 256) {
    const int j = item / 81, p = item % 81;
    const int p1 = p / 27, p2 = (p / 9) % 3, p3 = (p / 3) % 3, p4 = p % 3;
    int ym = 0, ny = 0;
    if (p1 == 2) { ym |= 8; ++ny; }
    if (p2 == 2) { ym |= 4; ++ny; }
    if (p3 == 2) { ym |= 2; ++ny; }
    if (p4 == 2) { ym |= 1; ++ny; }
    float sum = 0.f;
    for (int t = 0; t < 16; ++t) {
      const int t0 = (t>>3)&1, t1 = (t>>2)&1, t2 = (t>>1)&1, t3 = t&1;
      float sgn = 1.f;
      if      (p1 == 1) sgn *= t0 ? -1.f : 1.f;
      else if (p1 == 2) sgn *= t0 ?  1.f : -1.f;
      if      (p2 == 1) sgn *= t1 ? -1.f : 1.f;
      else if (p2 == 2) sgn *= t1 ?  1.f : -1.f;
      if      (p3 == 1) sgn *= t2 ? -1.f : 1.f;
      else if (p3 == 2) sgn *= t2 ?  1.f : -1.f;
      if      (p4 == 1) sgn *= t3 ? -1.f : 1.f;
      else if (p4 == 2) sgn *= t3 ?  1.f : -1.f;
      const float2 ae = A[j][t ^ ym][t];
      const int m = ny & 3;
      const float re = (m == 0) ? ae.x : (m == 1) ? -ae.y : (m == 2) ? -ae.x : ae.y;
      sum += sgn * re;
    }
    sum *= 0.0625f;
    if (p == 0) sum += bv[j];
    Dcoef[p*4 + j] = sum;
  }
}

__global__ __launch_bounds__(256) void qg_main(
    const float4* __restrict__ noise,   // [B] float4
    const float4* __restrict__ Dc,      // [81] float4
    float4* __restrict__ out,           // [B] float4
    int B)
{
  __shared__ float4 Dl[81];
  const int tid = threadIdx.x;
  if (tid < 81) Dl[tid] = Dc[tid];
  __syncthreads();

  const int base = blockIdx.x * 512 + tid;     // elem A; elem B = base+256
  const int ia = base < B ? base : B - 1;
  const int ib = (base + 256) < B ? (base + 256) : B - 1;
  const float4 xa = noise[ia];
  const float4 xb = noise[ib];

  float s0a,c0a,s1a,c1a,s2a,c2a,s3a,c3a;
  float s0b,c0b,s1b,c1b,s2b,c2b,s3b,c3b;
  __sincosf(xa.x, &s0a, &c0a);  __sincosf(xa.y, &s1a, &c1a);
  __sincosf(xa.z, &s2a, &c2a);  __sincosf(xa.w, &s3a, &c3a);
  __sincosf(xb.x, &s0b, &c0b);  __sincosf(xb.y, &s1b, &c1b);
  __sincosf(xb.z, &s2b, &c2b);  __sincosf(xb.w, &s3b, &c3b);

  // f = (1, cos, -sin); g12[a]=f1[a/3]*f2[a%3], g34[b]=f3[b/3]*f4[b%3]
  const float2 g34_1 = make_float2( c3a,      c3b);
  const float2 g34_2 = make_float2(-s3a,     -s3b);
  const float2 g34_3 = make_float2( c2a,      c2b);
  const float2 g34_4 = make_float2( c2a*c3a,  c2b*c3b);
  const float2 g34_5 = make_float2(-c2a*s3a, -c2b*s3b);
  const float2 g34_6 = make_float2(-s2a,     -s2b);
  const float2 g34_7 = make_float2(-s2a*c3a, -s2b*c3b);
  const float2 g34_8 = make_float2( s2a*s3a,  s2b*s3b);
  const float2 g12_1 = make_float2( c1a,      c1b);
  const float2 g12_2 = make_float2(-s1a,     -s1b);
  const float2 g12_3 = make_float2( c0a,      c0b);
  const float2 g12_4 = make_float2( c0a*c1a,  c0b*c1b);
  const float2 g12_5 = make_float2(-c0a*s1a, -c0b*s1b);
  const float2 g12_6 = make_float2(-s0a,     -s0b);
  const float2 g12_7 = make_float2(-s0a*c1a, -s0b*c1b);
  const float2 g12_8 = make_float2( s0a*s1a,  s0b*s1b);

  float2 h0, h1, h2, h3, acc0, acc1, acc2, acc3;

#define HT(a,b,G) { const float4 q = Dl[(a)*9+(b)];                 \
    h0.x = fmaf(q.x, G.x, h0.x); h0.y = fmaf(q.x, G.y, h0.y);       \
    h1.x = fmaf(q.y, G.x, h1.x); h1.y = fmaf(q.y, G.y, h1.y);       \
    h2.x = fmaf(q.z, G.x, h2.x); h2.y = fmaf(q.z, G.y, h2.y);       \
    h3.x = fmaf(q.w, G.x, h3.x); h3.y = fmaf(q.w, G.y, h3.y); }
#define HB(a) { const float4 q = Dl[(a)*9];                         \
    h0 = make_float2(q.x, q.x); h1 = make_float2(q.y, q.y);         \
    h2 = make_float2(q.z, q.z); h3 = make_float2(q.w, q.w); }       \
    HT(a,1,g34_1) HT(a,2,g34_2) HT(a,3,g34_3) HT(a,4,g34_4)         \
    HT(a,5,g34_5) HT(a,6,g34_6) HT(a,7,g34_7) HT(a,8,g34_8)
#define ACC(G) {                                                    \
    acc0.x = fmaf(G.x, h0.x, acc0.x); acc0.y = fmaf(G.y, h0.y, acc0.y); \
    acc1.x = fmaf(G.x, h1.x, acc1.x); acc1.y = fmaf(G.y, h1.y, acc1.y); \
    acc2.x = fmaf(G.x, h2.x, acc2.x); acc2.y = fmaf(G.y, h2.y, acc2.y); \
    acc3.x = fmaf(G.x, h3.x, acc3.x); acc3.y = fmaf(G.y, h3.y, acc3.y); }

  HB(0) acc0 = h0; acc1 = h1; acc2 = h2; acc3 = h3;
  HB(1) ACC(g12_1)
  HB(2) ACC(g12_2)
  HB(3) ACC(g12_3)
  HB(4) ACC(g12_4)
  HB(5) ACC(g12_5)
  HB(6) ACC(g12_6)
  HB(7) ACC(g12_7)
  HB(8) ACC(g12_8)

#undef HT
#undef HB
#undef ACC

  if (base < B)
    out[base] = make_float4(fabsf(acc0.x) + 0.001f, acc1.x, acc2.x, acc3.x);
  if (base + 256 < B)
    out[base + 256] = make_float4(fabsf(acc0.y) + 0.001f, acc1.y, acc2.y, acc3.y);
}

extern "C" void kernel_launch(void* const* d_in, const int* in_sizes, int n_in,
                              void* d_out, int out_size, void* d_ws, size_t ws_size,
                              hipStream_t stream) {
  const float* noise = (const float*)d_in[0];   // [B,4]
  const float* qw    = (const float*)d_in[1];   // [2,4,3]
  const float* Wm    = (const float*)d_in[2];   // [4,4]
  const float* bv    = (const float*)d_in[3];   // [4]
  float* Dcoef = (float*)d_ws;                  // 81*4 floats
  const int B = in_sizes[0] / 4;

  hipLaunchKernelGGL(qg_precompute, dim3(1), dim3(256), 0, stream, qw, Wm, bv, Dcoef);

  const int blocks = (B + 511) / 512;
  hipLaunchKernelGGL(qg_main, dim3(blocks), dim3(256), 0, stream,
                     (const float4*)noise, (const float4*)Dcoef, (float4*)d_out, B);
}